// Round 8
// baseline (127.955 us; speedup 1.0000x reference)
//
#include <hip/hip_runtime.h>
#include <hip/hip_bf16.h>
#include <math.h>

#define S_LEN  2048
#define DMODEL 512
#define NHEADS 8
#define DK     64
#define WIN    64

static constexpr float SCALE = 0.125f;

typedef short bf16x8 __attribute__((ext_vector_type(8)));
typedef float f32x4  __attribute__((ext_vector_type(4)));

// ---------------------------------------------------------------------------
// helpers
// ---------------------------------------------------------------------------
__device__ __forceinline__ short bfh(float v)
{
    __hip_bfloat16 b = __float2bfloat16(v);
    return *reinterpret_cast<short*>(&b);
}
__device__ __forceinline__ float bf2f(short s)
{
    __hip_bfloat16 b = *reinterpret_cast<__hip_bfloat16*>(&s);
    return __bfloat162float(b);
}
__device__ __forceinline__ void split1(float v, short& h, short& l)
{
    h = bfh(v);
    l = bfh(v - bf2f(h));
}

// round-half-up fp32->bf16, packed pair (error bound = RNE except exact ties)
__device__ __forceinline__ unsigned rhu2(float f0, float f1)
{
    unsigned b0, b1;
    __builtin_memcpy(&b0, &f0, 4);
    __builtin_memcpy(&b1, &f1, 4);
    return ((b1 + 0x8000u) & 0xffff0000u) | ((b0 + 0x8000u) >> 16);
}
// 8 fp32 -> bf16x8 fragment (round-half-up)
__device__ __forceinline__ bf16x8 packW(const float4 w0, const float4 w1)
{
    union { unsigned u[4]; bf16x8 v; } r;
    r.u[0] = rhu2(w0.x, w0.y);
    r.u[1] = rhu2(w0.z, w0.w);
    r.u[2] = rhu2(w1.x, w1.y);
    r.u[3] = rhu2(w1.z, w1.w);
    return r.v;
}
// 8 fp32 -> hi (round-half-up) + lo (RNE of residual)
__device__ __forceinline__ void splitx8(const float4 a0, const float4 a1,
                                        bf16x8& h8, bf16x8& l8)
{
    float f[8] = {a0.x, a0.y, a0.z, a0.w, a1.x, a1.y, a1.z, a1.w};
#pragma unroll
    for (int i = 0; i < 8; ++i) {
        unsigned b;
        __builtin_memcpy(&b, &f[i], 4);
        const unsigned hb = (b + 0x8000u) & 0xffff0000u;
        h8[i] = (short)(hb >> 16);
        float hf;
        __builtin_memcpy(&hf, &hb, 4);
        l8[i] = bfh(f[i] - hf);
    }
}

// async global->LDS, 16B per lane; lds dest = wave-uniform base + lane*16
__device__ __forceinline__ void dma16(const void* g, void* l)
{
    __builtin_amdgcn_global_load_lds(
        (const __attribute__((address_space(1))) unsigned int*)g,
        (__attribute__((address_space(3))) unsigned int*)l, 16, 0, 0);
}

// ---------------------------------------------------------------------------
// QKV GEMM. 32-row x 64-col tiles, grid (8,64,3) = 1536 blocks, 128 threads.
// W staged as fp32 via DMA, 4 phases x 32 KB (64 cols x 128 k), chunk
// XOR(n&7) swizzle; converted to bf16 at fragment-read (round-half-up pack).
// x read fp32 from global, split hi/lo in-register.
// z=0 -> Q (bf16 hi/lo), z=1 -> K (bf16), z=2 -> V^T (bf16, [dim][pos]).
// ---------------------------------------------------------------------------
__global__ __launch_bounds__(128)
void gemm_qkv5(const float* __restrict__ x,
               const float* __restrict__ Wqf, const float* __restrict__ Wkf,
               const float* __restrict__ Wvf,
               const float* __restrict__ bq, const float* __restrict__ bk,
               const float* __restrict__ bv,
               short* __restrict__ qh, short* __restrict__ ql,
               short* __restrict__ kb, short* __restrict__ vbt)
{
    __shared__ __align__(16) float sW[64 * 128];   // 32 KB: 64 rows x 128 k fp32

    const int z = blockIdx.z;
    const float* Wg   = (z == 0) ? Wqf : (z == 1) ? Wkf : Wvf;
    const float* bias = (z == 0) ? bq  : (z == 1) ? bk  : bv;
    const int row0 = blockIdx.y * 32;
    const int col0 = blockIdx.x * 64;
    const int tid  = threadIdx.x;
    const int lane = tid & 63;
    const int wv   = tid >> 6;
    const int col  = lane & 15;
    const int quad = lane >> 4;
    const int m    = row0 + wv * 16 + col;     // this wave's A row

    f32x4 acc[4];
#pragma unroll
    for (int nj = 0; nj < 4; ++nj)
        acc[nj] = (f32x4)0.0f;

    for (int ph = 0; ph < 4; ++ph) {
        __syncthreads();   // previous phase's LDS reads complete
        // stage 64 rows x 32 chunks (16B) of W fp32; issue covers 2 rows
        for (int i = wv; i < 32; i += 2) {
            const int r = 2 * i + (lane >> 5);
            const int c = lane & 31;
            const int j = c ^ (r & 7);
            dma16(Wg + (size_t)(col0 + r) * 512 + ph * 128 + j * 4, sW + i * 256);
        }
        __syncthreads();   // vmcnt(0) drain

#pragma unroll
        for (int kc = 0; kc < 4; ++kc) {
            const int k = ph * 128 + kc * 32;
            const float* xp = x + (size_t)m * 512 + k + quad * 8;
            const float4 a0 = *(const float4*)xp;
            const float4 a1 = *(const float4*)(xp + 4);
            bf16x8 ah, al;
            splitx8(a0, a1, ah, al);
#pragma unroll
            for (int nj = 0; nj < 4; ++nj) {
                const int n  = nj * 16 + col;
                const int s  = n & 7;
                const int c0 = kc * 8 + quad * 2;
                const float4 w0 = *(const float4*)&sW[n * 128 + ((c0    ) ^ s) * 4];
                const float4 w1 = *(const float4*)&sW[n * 128 + ((c0 + 1) ^ s) * 4];
                const bf16x8 wf = packW(w0, w1);
                acc[nj] = __builtin_amdgcn_mfma_f32_16x16x32_bf16(ah, wf, acc[nj], 0, 0, 0);
                acc[nj] = __builtin_amdgcn_mfma_f32_16x16x32_bf16(al, wf, acc[nj], 0, 0, 0);
            }
        }
    }

    // epilogue
#pragma unroll
    for (int nj = 0; nj < 4; ++nj) {
        const int cc = col0 + nj * 16 + col;
        const float bias_v = bias[cc];
#pragma unroll
        for (int e = 0; e < 4; ++e) {
            const int row = row0 + wv * 16 + quad * 4 + e;
            const float val = acc[nj][e] + bias_v;
            if (z == 0) {
                short hh, ll;
                split1(val, hh, ll);
                qh[(size_t)row * 512 + cc] = hh;
                ql[(size_t)row * 512 + cc] = ll;
            } else if (z == 1) {
                kb[(size_t)row * 512 + cc] = bfh(val);
            } else {
                vbt[(size_t)cc * 2048 + row] = bfh(val);   // transposed
            }
        }
    }
}

// ---------------------------------------------------------------------------
// Output projection: A = attention output (bf16, global), W = Wo fp32 staged.
// 32-row x 64-col tiles, grid (8,64) = 512 blocks, 128 threads.
// ---------------------------------------------------------------------------
__global__ __launch_bounds__(128)
void gemm_out5(const short* __restrict__ ah_g,
               const float* __restrict__ Wof, const float* __restrict__ bo,
               float* __restrict__ out)
{
    __shared__ __align__(16) float sW[64 * 128];

    const int row0 = blockIdx.y * 32;
    const int col0 = blockIdx.x * 64;
    const int tid  = threadIdx.x;
    const int lane = tid & 63;
    const int wv   = tid >> 6;
    const int col  = lane & 15;
    const int quad = lane >> 4;
    const int m    = row0 + wv * 16 + col;

    f32x4 acc[4];
#pragma unroll
    for (int nj = 0; nj < 4; ++nj)
        acc[nj] = (f32x4)0.0f;

    for (int ph = 0; ph < 4; ++ph) {
        __syncthreads();
        for (int i = wv; i < 32; i += 2) {
            const int r = 2 * i + (lane >> 5);
            const int c = lane & 31;
            const int j = c ^ (r & 7);
            dma16(Wof + (size_t)(col0 + r) * 512 + ph * 128 + j * 4, sW + i * 256);
        }
        __syncthreads();

#pragma unroll
        for (int kc = 0; kc < 4; ++kc) {
            const int k = ph * 128 + kc * 32;
            const bf16x8 af = *(const bf16x8*)(ah_g + (size_t)m * 512 + k + quad * 8);
#pragma unroll
            for (int nj = 0; nj < 4; ++nj) {
                const int n  = nj * 16 + col;
                const int s  = n & 7;
                const int c0 = kc * 8 + quad * 2;
                const float4 w0 = *(const float4*)&sW[n * 128 + ((c0    ) ^ s) * 4];
                const float4 w1 = *(const float4*)&sW[n * 128 + ((c0 + 1) ^ s) * 4];
                const bf16x8 wf = packW(w0, w1);
                acc[nj] = __builtin_amdgcn_mfma_f32_16x16x32_bf16(af, wf, acc[nj], 0, 0, 0);
            }
        }
    }

#pragma unroll
    for (int nj = 0; nj < 4; ++nj) {
        const int cc = col0 + nj * 16 + col;
        const float bias_v = bo[cc];
#pragma unroll
        for (int e = 0; e < 4; ++e) {
            const int row = row0 + wv * 16 + quad * 4 + e;
            out[(size_t)row * 512 + cc] = acc[nj][e] + bias_v;
        }
    }
}

// ---------------------------------------------------------------------------
// MFMA banded attention (round-7 body, unchanged).
// ---------------------------------------------------------------------------
__global__ __launch_bounds__(256)
void banded_attn4(const short* __restrict__ qh, const short* __restrict__ ql,
                  const short* __restrict__ kb, const short* __restrict__ vbt,
                  short* __restrict__ abh)
{
    __shared__ __align__(16) short VtS[64 * 256];   // V^T [dim][32 chunks]
    __shared__ __align__(16) short KS [192 * 64];   // K window; aliased by P
    __shared__ __align__(16) short QhS[32 * 64];
    __shared__ __align__(16) short QlS[32 * 64];
    __shared__ float pmax[4][32];
    __shared__ float psum[4][32];
    short* PS = KS;                                 // P [32][200], after QK

    const int h    = blockIdx.x;
    const int t0   = blockIdx.y * 32;
    const int tid  = threadIdx.x;
    const int lane = tid & 63;
    const int wv   = tid >> 6;
    const int col  = lane & 15;
    const int quad = lane >> 4;

    // ---- DMA staging: Qh (4 issues), Ql (4), K (24) — 8-row groups ----
    {
        const int lr = lane >> 3;
        const int lc = lane & 7;
        for (int i = wv; i < 32; i += 4) {
            const short* src; short* dst; int r;
            if (i < 4) {
                r = i * 8 + lr;
                src = qh + (size_t)(t0 + r) * 512 + h * 64;
                dst = QhS + i * 512;
            } else if (i < 8) {
                const int g = i - 4;
                r = g * 8 + lr;
                src = ql + (size_t)(t0 + r) * 512 + h * 64;
                dst = QlS + g * 512;
            } else {
                const int g = i - 8;
                r = g * 8 + lr;
                int pos = t0 - 64 + r;
                pos = pos < 0 ? 0 : (pos > 2047 ? 2047 : pos);   // masked later
                src = kb + (size_t)pos * 512 + h * 64;
                dst = KS + g * 512;
            }
            const int cs = lc ^ (r & 7);
            dma16(src + cs * 8, dst);
        }
        // ---- V^T window: 64 dims x 24 chunks (192 pos), rows padded to 32 ----
        for (int i = wv; i < 32; i += 4) {
            const int q = i * 64 + lane;
            const int d = q >> 5;            // dim 0..63
            const int b = q & 31;            // dest chunk in row
            const int j0 = (b < 24) ? b : 0; // dead chunks load dummy
            const int j = j0 ^ (d & 7);
            int p0 = t0 - 64 + j * 8;
            p0 = p0 < 0 ? 0 : (p0 > 2040 ? 2040 : p0);
            dma16(vbt + (size_t)(h * 64 + d) * 2048 + p0, VtS + i * 512);
        }
    }
    __syncthreads();

    // ---- QK^T: wave covers positions [wv*48, wv*48+48) ----
    f32x4 sacc[2][3];
#pragma unroll
    for (int mi = 0; mi < 2; ++mi)
#pragma unroll
        for (int nj = 0; nj < 3; ++nj)
            sacc[mi][nj] = (f32x4)0.0f;

#pragma unroll
    for (int ks = 0; ks < 2; ++ks) {
        const int q0 = ks * 4 + quad;
        bf16x8 aqh[2], aql[2];
#pragma unroll
        for (int mi = 0; mi < 2; ++mi) {
            const int m = mi * 16 + col;
            const int p = q0 ^ (m & 7);
            aqh[mi] = *(const bf16x8*)&QhS[m * 64 + p * 8];
            aql[mi] = *(const bf16x8*)&QlS[m * 64 + p * 8];
        }
#pragma unroll
        for (int nj = 0; nj < 3; ++nj) {
            const int n = wv * 48 + nj * 16 + col;
            const int p = q0 ^ (n & 7);
            const bf16x8 bkf = *(const bf16x8*)&KS[n * 64 + p * 8];
#pragma unroll
            for (int mi = 0; mi < 2; ++mi) {
                sacc[mi][nj] = __builtin_amdgcn_mfma_f32_16x16x32_bf16(aqh[mi], bkf, sacc[mi][nj], 0, 0, 0);
                sacc[mi][nj] = __builtin_amdgcn_mfma_f32_16x16x32_bf16(aql[mi], bkf, sacc[mi][nj], 0, 0, 0);
            }
        }
    }

    // ---- mask + scale ----
    float pv[2][3][4];
#pragma unroll
    for (int mi = 0; mi < 2; ++mi)
#pragma unroll
        for (int nj = 0; nj < 3; ++nj)
#pragma unroll
            for (int e = 0; e < 4; ++e) {
                const int r32 = mi * 16 + quad * 4 + e;
                const int n   = wv * 48 + nj * 16 + col;
                const int pos = t0 - 64 + n;
                const int d   = n - r32;
                const bool valid = (pos >= 0) && (pos < S_LEN) && (d >= 0) && (d <= 128);
                pv[mi][nj][e] = valid ? sacc[mi][nj][e] * SCALE : -__builtin_inff();
            }

    // ---- wave-partial row max ----
#pragma unroll
    for (int mi = 0; mi < 2; ++mi)
#pragma unroll
        for (int e = 0; e < 4; ++e) {
            float mx = fmaxf(fmaxf(pv[mi][0][e], pv[mi][1][e]), pv[mi][2][e]);
#pragma unroll
            for (int off = 1; off < 16; off <<= 1)
                mx = fmaxf(mx, __shfl_xor(mx, off));
            if ((lane & 15) == 0) pmax[wv][mi * 16 + quad * 4 + e] = mx;
        }
    __syncthreads();   // pmax done; K/Q reads done -> P may overwrite KS

    // ---- exp + wave-partial sums + write P (single bf16) ----
#pragma unroll
    for (int mi = 0; mi < 2; ++mi)
#pragma unroll
        for (int e = 0; e < 4; ++e) {
            const int r32 = mi * 16 + quad * 4 + e;
            const float m = fmaxf(fmaxf(pmax[0][r32], pmax[1][r32]),
                                  fmaxf(pmax[2][r32], pmax[3][r32]));
            float ss = 0.f;
#pragma unroll
            for (int nj = 0; nj < 3; ++nj) {
                const float p = __expf(pv[mi][nj][e] - m);
                pv[mi][nj][e] = p;
                ss += p;
            }
#pragma unroll
            for (int off = 1; off < 16; off <<= 1)
                ss += __shfl_xor(ss, off);
            if ((lane & 15) == 0) psum[wv][r32] = ss;
#pragma unroll
            for (int nj = 0; nj < 3; ++nj) {
                const int n = wv * 48 + nj * 16 + col;
                PS[r32 * 200 + n] = bfh(pv[mi][nj][e]);
            }
        }
    __syncthreads();

    // ---- PV ----
    const int mi = wv >> 1;
    f32x4 oacc[2];
    oacc[0] = (f32x4)0.0f;
    oacc[1] = (f32x4)0.0f;
#pragma unroll
    for (int ks = 0; ks < 6; ++ks) {
        const bf16x8 pa = *(const bf16x8*)&PS[(mi * 16 + col) * 200 + ks * 32 + quad * 8];
#pragma unroll
        for (int t = 0; t < 2; ++t) {
            const int d = ((wv & 1) * 2 + t) * 16 + col;
            const int j = (ks * 4 + quad) ^ (d & 7);
            const bf16x8 vf = *(const bf16x8*)&VtS[d * 256 + j * 8];
            oacc[t] = __builtin_amdgcn_mfma_f32_16x16x32_bf16(pa, vf, oacc[t], 0, 0, 0);
        }
    }

    // ---- epilogue: normalize, write single bf16 for out-GEMM ----
    float linv[4];
#pragma unroll
    for (int e = 0; e < 4; ++e) {
        const int r32 = mi * 16 + quad * 4 + e;
        linv[e] = 1.0f / (psum[0][r32] + psum[1][r32] + psum[2][r32] + psum[3][r32]);
    }
#pragma unroll
    for (int t = 0; t < 2; ++t) {
        const int nj = (wv & 1) * 2 + t;
#pragma unroll
        for (int e = 0; e < 4; ++e) {
            const int r32 = mi * 16 + quad * 4 + e;
            const float val = oacc[t][e] * linv[e];
            const size_t idx = (size_t)(t0 + r32) * 512 + h * 64 + nj * 16 + col;
            abh[idx] = bfh(val);
        }
    }
}

// ---------------------------------------------------------------------------
extern "C" void kernel_launch(void* const* d_in, const int* in_sizes, int n_in,
                              void* d_out, int out_size, void* d_ws, size_t ws_size,
                              hipStream_t stream)
{
    const float* x  = (const float*)d_in[0];
    const float* Wq = (const float*)d_in[1];
    const float* bq = (const float*)d_in[2];
    const float* Wk = (const float*)d_in[3];
    const float* bk = (const float*)d_in[4];
    const float* Wv = (const float*)d_in[5];
    const float* bv = (const float*)d_in[6];
    const float* Wo = (const float*)d_in[7];
    const float* bo = (const float*)d_in[8];
    float* out = (float*)d_out;

    char* ws = (char*)d_ws;
    short* qh  = (short*)(ws);                          // 2 MB
    short* ql  = (short*)(ws + (2u << 20));             // 2 MB
    short* kb  = (short*)(ws + (4u << 20));             // 2 MB
    short* vbt = (short*)(ws + (6u << 20));             // 2 MB (transposed V)
    short* abh = (short*)(ws + (8u << 20));             // 2 MB (attn out bf16)

    dim3 gq(DMODEL / 64, S_LEN / 32, 3);                // 8 x 64 x 3 = 1536 blocks
    gemm_qkv5<<<gq, 128, 0, stream>>>(x, Wq, Wk, Wv,
                                      bq, bk, bv, qh, ql, kb, vbt);

    dim3 ga(NHEADS, S_LEN / 32);                        // 512 blocks
    banded_attn4<<<ga, 256, 0, stream>>>(qh, ql, kb, vbt, abh);

    dim3 go(DMODEL / 64, S_LEN / 32);                   // 8 x 64 = 512 blocks
    gemm_out5<<<go, 128, 0, stream>>>(abh, Wo, bo, out);
}